// Round 3
// baseline (632.151 us; speedup 1.0000x reference)
//
#include <hip/hip_runtime.h>
#include <stdint.h>

// ---- problem constants ----
#define M_ROWS   224        // B*N = 32*7
#define K_DIM    49152      // D_MODEL*PATCH_NUMS
#define NCOL     1344       // 4 bands * 336
#define PRED     336
#define S_CHUNKS 48         // 21*48 = 1008 blocks = 3.94/CU (restore TLP)
#define STEPS    32         // K-steps of 32 per chunk: 1536/48... 48*1024/32

// ws layout: P (bf16 partials, 29 MB) at 0. X conversion fused into GEMM.

typedef __attribute__((ext_vector_type(8))) short short8;
typedef __attribute__((ext_vector_type(4))) float floatx4;

__device__ __forceinline__ uint16_t f32_to_bf16(float f) {
    uint32_t u = __builtin_bit_cast(uint32_t, f);
    uint32_t r = (u + 0x7fffu + ((u >> 16) & 1u)) >> 16;   // RNE
    return (uint16_t)r;
}
__device__ __forceinline__ float bf16_to_f32(uint16_t h) {
    uint32_t u = ((uint32_t)h) << 16;
    return __builtin_bit_cast(float, u);
}
__device__ __forceinline__ uint32_t pack2(float lo, float hi) {
    uint32_t r = (uint32_t)f32_to_bf16(lo) | ((uint32_t)f32_to_bf16(hi) << 16);
    return r;
}

// ======================= Kernel 1: split-K GEMM, fused X-fp32->bf16 staging ====
// 1008 blocks. id&7 ~ XCD: all 21 col-tiles of chunk s on one XCD -> per-step
// X slice (28 KB fp32) HBM-read once per XCD, L2-served 21x (lockstep sweep).
// Sync: raw s_barrier with lgkmcnt(0) only -- NO vmcnt drain (T4). Global
// prefetches stay in flight across barriers:
//   W: 2-deep ping-pong (wA/wB, reloaded for st+2 right after consumption)
//   X: 1-deep (L2-hot), issued BEFORE W so the pre-ds_write wait is
//      vmcnt(8) = X only; W remains outstanding.
// One barrier/step is race-free: lgkmcnt(0) before s_barrier completes every
// wave's LDS reads+writes before any wave passes.
__global__ __launch_bounds__(256, 4) void gemm_partial(
    const float* __restrict__ X,      // (224, 49152) fp32
    const float* __restrict__ W,      // (4, 49152, 336) fp32
    uint16_t* __restrict__ P)         // (224, 48, 1344) bf16 partials
{
    __shared__ uint16_t lA[2][14 * 512];     // 2 x 14 KB, fragment-ordered

    const int id = blockIdx.x;
    const int g  = id & 7;                   // presumed XCD
    const int q  = id >> 3;                  // 0..125
    const int ct = q % 21;                   // col-tile 0..20
    const int s  = g + 8 * (q / 21);         // K-chunk 0..47, s%8 == XCD

    const int tid  = threadIdx.x;
    const int lane = tid & 63;
    const int w    = tid >> 6;
    const int l15  = lane & 15;
    const int kq   = lane >> 4;
    const int c0w  = ct * 64 + w * 16;
    const int band = c0w / PRED;             // 16 | 336 -> no band straddle
    const int p0   = c0w - band * PRED;

    const float* wbase = W + (size_t)band * ((size_t)K_DIM * PRED)
                           + (size_t)(kq * 8) * PRED
                           + (size_t)(p0 + l15);
    const float* xbase = X + (size_t)l15 * K_DIM + (size_t)(kq * 8);
    const int kbase = s * (STEPS * 32);

    floatx4 acc[14];
    #pragma unroll
    for (int f = 0; f < 14; ++f) acc[f] = (floatx4){0.f, 0.f, 0.f, 0.f};

    float wA[8], wB[8];                       // 2-deep W ping-pong
    float4 xr[4][2];                          // in-flight fp32 A slices

    // ---- prologue: X(0) first (so its wait leaves W in flight), W(0)->wA,
    //      W(1)->wB, pack X(0) -> buf0 ----
    #pragma unroll
    for (int t = 0; t < 4; ++t) {
        const int f = w + 4 * t;
        if (f < 14) {
            const float* gp = xbase + (size_t)(16 * f) * K_DIM + kbase;
            xr[t][0] = *(const float4*)gp;
            xr[t][1] = *(const float4*)(gp + 4);
        }
    }
    #pragma unroll
    for (int j = 0; j < 8; ++j) wA[j] = wbase[(size_t)(kbase + j) * PRED];
    #pragma unroll
    for (int j = 0; j < 8; ++j) wB[j] = wbase[(size_t)(kbase + 32 + j) * PRED];
    #pragma unroll
    for (int t = 0; t < 4; ++t) {
        const int f = w + 4 * t;
        if (f < 14) {
            short8 v;
            ((uint32_t*)&v)[0] = pack2(xr[t][0].x, xr[t][0].y);
            ((uint32_t*)&v)[1] = pack2(xr[t][0].z, xr[t][0].w);
            ((uint32_t*)&v)[2] = pack2(xr[t][1].x, xr[t][1].y);
            ((uint32_t*)&v)[3] = pack2(xr[t][1].z, xr[t][1].w);
            *(short8*)&lA[0][f * 512 + lane * 8] = v;
        }
    }
    asm volatile("s_waitcnt lgkmcnt(0)" ::: "memory");
    __builtin_amdgcn_s_barrier();

    // One step: pack bfrag(WREG) | issue X(ST+1) | reissue W(ST+2)->WREG |
    //           MFMA on lA[RBUF] | pack xr -> lA[WBUF] | lgkm(0) barrier
#define GEMM_STEP(WREG, RBUF, WBUF, ST)                                        \
    {                                                                          \
        short8 bfrag;                                                          \
        _Pragma("unroll")                                                      \
        for (int j = 0; j < 4; ++j)                                            \
            ((uint32_t*)&bfrag)[j] = pack2(WREG[2*j], WREG[2*j+1]);            \
        if ((ST) + 1 < STEPS) {                                                \
            const int kx = kbase + ((ST) + 1) * 32;                            \
            _Pragma("unroll")                                                  \
            for (int t = 0; t < 4; ++t) {                                      \
                const int f = w + 4 * t;                                       \
                if (f < 14) {                                                  \
                    const float* gp = xbase + (size_t)(16 * f) * K_DIM + kx;   \
                    xr[t][0] = *(const float4*)gp;                             \
                    xr[t][1] = *(const float4*)(gp + 4);                       \
                }                                                              \
            }                                                                  \
        }                                                                      \
        if ((ST) + 2 < STEPS) {                                                \
            const int kw2 = kbase + ((ST) + 2) * 32;                           \
            _Pragma("unroll")                                                  \
            for (int j = 0; j < 8; ++j)                                        \
                WREG[j] = wbase[(size_t)(kw2 + j) * PRED];                     \
        }                                                                      \
        _Pragma("unroll")                                                      \
        for (int f = 0; f < 14; ++f) {                                         \
            short8 afrag = *(const short8*)&lA[RBUF][f * 512 + lane * 8];      \
            acc[f] = __builtin_amdgcn_mfma_f32_16x16x32_bf16(                  \
                afrag, bfrag, acc[f], 0, 0, 0);                                \
        }                                                                      \
        if ((ST) + 1 < STEPS) {                                                \
            _Pragma("unroll")                                                  \
            for (int t = 0; t < 4; ++t) {                                      \
                const int f = w + 4 * t;                                       \
                if (f < 14) {                                                  \
                    short8 v;                                                  \
                    ((uint32_t*)&v)[0] = pack2(xr[t][0].x, xr[t][0].y);        \
                    ((uint32_t*)&v)[1] = pack2(xr[t][0].z, xr[t][0].w);        \
                    ((uint32_t*)&v)[2] = pack2(xr[t][1].x, xr[t][1].y);        \
                    ((uint32_t*)&v)[3] = pack2(xr[t][1].z, xr[t][1].w);        \
                    *(short8*)&lA[WBUF][f * 512 + lane * 8] = v;               \
                }                                                              \
            }                                                                  \
        }                                                                      \
        asm volatile("s_waitcnt lgkmcnt(0)" ::: "memory");                     \
        __builtin_amdgcn_s_barrier();                                          \
    }

    for (int st = 0; st < STEPS; st += 2) {
        GEMM_STEP(wA, 0, 1, st)          // even step: read buf0, write buf1
        GEMM_STEP(wB, 1, 0, st + 1)      // odd step: read buf1, write buf0
    }
#undef GEMM_STEP

    // ---- write bf16 partials: C/D layout col=lane&15, row=kq*4+reg ----
    const int col = c0w + l15;
    #pragma unroll
    for (int f = 0; f < 14; ++f) {
        #pragma unroll
        for (int r = 0; r < 4; ++r) {
            const int m = 16 * f + kq * 4 + r;
            P[((size_t)m * S_CHUNKS + s) * NCOL + col] = f32_to_bf16(acc[f][r]);
        }
    }
}

// ======================= Kernel 2: partial reduce + bias + iSWT =======================
__device__ const float REC_LO[8] = {
     0.23037781330885523f,  0.7148465705525415f,   0.6308807679295904f,
    -0.02798376941698385f, -0.18703481171888114f,  0.030841381835986965f,
     0.032883011666982945f, -0.010597401784997278f };
__device__ const float REC_HI[8] = {
     0.010597401784997278f, 0.032883011666982945f, -0.030841381835986965f,
    -0.18703481171888114f,  0.02798376941698385f,   0.6308807679295904f,
    -0.7148465705525415f,   0.23037781330885523f };

__global__ __launch_bounds__(1024) void reduce_iswt(
    const uint16_t* __restrict__ P,    // (224, 48, 1344) bf16
    const float* __restrict__ bias,    // (4, 336) flat == flat col
    float* __restrict__ out)           // (224, 336)
{
    __shared__ float coeff[NCOL];
    __shared__ float buf[2][PRED];

    const int row = blockIdx.x;
    const int tid = threadIdx.x;
    const uint32_t* pr = (const uint32_t*)(P + (size_t)row * S_CHUNKS * NCOL);

    if (tid < NCOL / 2) {
        float a0 = 0.f, a1 = 0.f;
        #pragma unroll 8
        for (int s = 0; s < S_CHUNKS; ++s) {
            const uint32_t v = pr[s * (NCOL / 2) + tid];
            a0 += bf16_to_f32((uint16_t)(v & 0xffff));
            a1 += bf16_to_f32((uint16_t)(v >> 16));
        }
        coeff[2 * tid]     = a0 + bias[2 * tid];
        coeff[2 * tid + 1] = a1 + bias[2 * tid + 1];
    }
    __syncthreads();

    if (tid < PRED) buf[0][tid] = coeff[tid];   // band 0 = cA
    __syncthreads();

    int curb = 0;
    for (int j = 3; j >= 1; --j) {
        const int step = 1 << (j - 1);              // 4, 2, 1
        const int M    = PRED / step;               // 84, 168, 336
        const float* cd  = &coeff[(4 - j) * PRED];  // cD3, cD2, cD1
        const float* cur = buf[curb];
        float* nxt       = buf[curb ^ 1];
        if (tid < PRED) {
            const int t = tid;
            const int sidx = t & (step - 1);
            const int m = t / step;
            const int mm1 = (m == 0) ? (M - 1) : (m - 1);
            float x1 = 0.f, x2 = 0.f;
            #pragma unroll
            for (int k = 0; k < 8; ++k) {
                int i1 = m + 3 - k;  if (i1 < 0) i1 += M; else if (i1 >= M) i1 -= M;
                if ((i1 & 1) == 0) {
                    const int pos = i1 * step + sidx;
                    x1 += cur[pos] * REC_LO[k] + cd[pos] * REC_HI[k];
                }
                int i2 = mm1 + 3 - k;  if (i2 < 0) i2 += M; else if (i2 >= M) i2 -= M;
                if ((i2 & 1) == 0) {
                    const int pos = (i2 + 1) * step + sidx;
                    x2 += cur[pos] * REC_LO[k] + cd[pos] * REC_HI[k];
                }
            }
            nxt[t] = 0.5f * (x1 + x2);
        }
        __syncthreads();
        curb ^= 1;
    }

    if (tid < PRED) out[(size_t)row * PRED + tid] = buf[curb][tid];
}

// ======================= launch =======================
extern "C" void kernel_launch(void* const* d_in, const int* in_sizes, int n_in,
                              void* d_out, int out_size, void* d_ws, size_t ws_size,
                              hipStream_t stream) {
    const float* X    = (const float*)d_in[0];   // (224, 49152)
    const float* W    = (const float*)d_in[1];   // (4, 49152, 336)
    const float* bias = (const float*)d_in[2];   // (4, 336)
    float* out        = (float*)d_out;           // (224, 336)
    uint16_t* P       = (uint16_t*)d_ws;         // 29 MB partials

    gemm_partial<<<21 * S_CHUNKS, 256, 0, stream>>>(X, W, P);
    reduce_iswt <<<M_ROWS, 1024, 0, stream>>>(P, bias, out);
}

// Round 4
// 429.162 us; speedup vs baseline: 1.4730x; 1.4730x over previous
//
#include <hip/hip_runtime.h>
#include <stdint.h>

// ---- problem constants ----
#define M_ROWS   224        // B*N = 32*7
#define K_DIM    49152      // D_MODEL*PATCH_NUMS
#define NCOL     1344       // 4 bands * 336
#define PRED     336
#define S_CHUNKS 48         // 21*48 = 1008 blocks = 3.94/CU
#define STEPS    32         // K-steps of 32 per chunk

// ws layout: P (bf16 partials, 29 MB) at 0; Xbf16 (22 MB) at 32 MB
#define XB_OFFSET (32u * 1024u * 1024u)

typedef __attribute__((ext_vector_type(8))) short short8;
typedef __attribute__((ext_vector_type(4))) float floatx4;

__device__ __forceinline__ uint16_t f32_to_bf16(float f) {
    uint32_t u = __builtin_bit_cast(uint32_t, f);
    uint32_t r = (u + 0x7fffu + ((u >> 16) & 1u)) >> 16;   // RNE
    return (uint16_t)r;
}
__device__ __forceinline__ float bf16_to_f32(uint16_t h) {
    uint32_t u = ((uint32_t)h) << 16;
    return __builtin_bit_cast(float, u);
}
__device__ __forceinline__ uint32_t pack2(float lo, float hi) {
    return (uint32_t)f32_to_bf16(lo) | ((uint32_t)f32_to_bf16(hi) << 16);
}

// ======================= Kernel 0: X fp32 -> bf16 =======================
__global__ __launch_bounds__(256) void cvt_x(
    const float* __restrict__ X, uint16_t* __restrict__ Xb)
{
    const size_t i = ((size_t)blockIdx.x * 256 + threadIdx.x) * 8;
    const float4 a = *(const float4*)(X + i);
    const float4 b = *(const float4*)(X + i + 4);
    uint4 o;
    o.x = pack2(a.x, a.y);
    o.y = pack2(a.z, a.w);
    o.z = pack2(b.x, b.y);
    o.w = pack2(b.z, b.w);
    *(uint4*)(Xb + i) = o;
}

// ======================= Kernel 1: split-K GEMM, glds staging, counted vmcnt ====
// Baseline structure (glds, S=48, 4 blk/CU) + T4 counted waits:
//   per step: issue glds(st+1) FIRST, then 8 W dword loads (st+2, ping-pong
//   wA/wB). End-of-step waits vmcnt(8) -- drains the glds (oldest in queue)
//   while W loads stay in flight ACROSS the barrier. No vmcnt(0) in the loop.
// Race-freedom: all ds_reads feed MFMAs in-step (compiler lgkm waits), so
// LDS reads of buf[cur] complete before the barrier; vmcnt(8) completes all
// glds writes of buf^1 before any wave reads it next step.
__global__ __launch_bounds__(256, 4) void gemm_partial(
    const uint16_t* __restrict__ Xb,  // (224, 49152) bf16
    const float* __restrict__ W,      // (4, 49152, 336) fp32
    uint16_t* __restrict__ P)         // (224, 48, 1344) bf16 partials
{
    __shared__ uint16_t lA[2][14 * 512];     // 2 x 14 KB, fragment-ordered

    const int id = blockIdx.x;
    const int g  = id & 7;                   // presumed XCD
    const int q  = id >> 3;                  // 0..125
    const int ct = q % 21;                   // col-tile 0..20
    const int s  = g + 8 * (q / 21);         // K-chunk 0..47, s%8 == XCD

    const int tid  = threadIdx.x;
    const int lane = tid & 63;
    const int w    = tid >> 6;
    const int l15  = lane & 15;
    const int kq   = lane >> 4;
    const int c0w  = ct * 64 + w * 16;
    const int band = c0w / PRED;             // 16 | 336 -> no band straddle
    const int p0   = c0w - band * PRED;

    const float* wbase = W + (size_t)band * ((size_t)K_DIM * PRED)
                           + (size_t)(kq * 8) * PRED
                           + (size_t)(p0 + l15);
    const size_t grow = (size_t)l15 * K_DIM + (size_t)kq * 8;
    const int kbase = s * (STEPS * 32);

    floatx4 acc[14];
    #pragma unroll
    for (int f = 0; f < 14; ++f) acc[f] = (floatx4){0.f, 0.f, 0.f, 0.f};

    float wA[8], wB[8];                      // 2-deep W ping-pong

    // ---- prologue: glds(0) first, then W(0)->wA, W(1)->wB ----
    #pragma unroll
    for (int t = 0; t < 4; ++t) {
        const int f = w + 4 * t;
        if (f < 14) {
            const uint16_t* gp = Xb + (size_t)(16 * f) * K_DIM + grow + kbase;
            __builtin_amdgcn_global_load_lds(
                (const __attribute__((address_space(1))) void*)gp,
                (__attribute__((address_space(3))) void*)&lA[0][f * 512],
                16, 0, 0);
        }
    }
    #pragma unroll
    for (int j = 0; j < 8; ++j) wA[j] = wbase[(size_t)(kbase + j) * PRED];
    #pragma unroll
    for (int j = 0; j < 8; ++j) wB[j] = wbase[(size_t)(kbase + 32 + j) * PRED];
    asm volatile("s_waitcnt vmcnt(16)" ::: "memory");   // drain glds; keep wA/wB
    __builtin_amdgcn_s_barrier();
    __builtin_amdgcn_sched_barrier(0);

    // One step: pack bfrag(WREG) | glds(ST+1)->WBUF | reissue W(ST+2)->WREG |
    //           MFMA on lA[RBUF] | vmcnt(8) lgkm(0) barrier
#define GEMM_STEP(WREG, RBUF, WBUF, ST)                                        \
    {                                                                          \
        short8 bfrag;                                                          \
        _Pragma("unroll")                                                      \
        for (int j = 0; j < 4; ++j)                                            \
            ((uint32_t*)&bfrag)[j] = pack2(WREG[2*j], WREG[2*j+1]);            \
        if ((ST) + 1 < STEPS) {                                                \
            const int kx = kbase + ((ST) + 1) * 32;                            \
            _Pragma("unroll")                                                  \
            for (int t = 0; t < 4; ++t) {                                      \
                const int f = w + 4 * t;                                       \
                if (f < 14) {                                                  \
                    const uint16_t* gp = Xb + (size_t)(16 * f) * K_DIM + grow + kx; \
                    __builtin_amdgcn_global_load_lds(                          \
                        (const __attribute__((address_space(1))) void*)gp,     \
                        (__attribute__((address_space(3))) void*)&lA[WBUF][f * 512], \
                        16, 0, 0);                                             \
                }                                                              \
            }                                                                  \
        }                                                                      \
        if ((ST) + 2 < STEPS) {                                                \
            const int kw2 = kbase + ((ST) + 2) * 32;                           \
            _Pragma("unroll")                                                  \
            for (int j = 0; j < 8; ++j)                                        \
                WREG[j] = wbase[(size_t)(kw2 + j) * PRED];                     \
        }                                                                      \
        _Pragma("unroll")                                                      \
        for (int f = 0; f < 14; ++f) {                                         \
            short8 afrag = *(const short8*)&lA[RBUF][f * 512 + lane * 8];      \
            acc[f] = __builtin_amdgcn_mfma_f32_16x16x32_bf16(                  \
                afrag, bfrag, acc[f], 0, 0, 0);                                \
        }                                                                      \
        asm volatile("s_waitcnt vmcnt(8) lgkmcnt(0)" ::: "memory");            \
        __builtin_amdgcn_s_barrier();                                          \
        __builtin_amdgcn_sched_barrier(0);                                     \
    }

    for (int st = 0; st < STEPS; st += 2) {
        GEMM_STEP(wA, 0, 1, st)          // even step: read buf0, fill buf1
        GEMM_STEP(wB, 1, 0, st + 1)      // odd step: read buf1, fill buf0
    }
#undef GEMM_STEP

    // ---- write bf16 partials: C/D layout col=lane&15, row=kq*4+reg ----
    const int col = c0w + l15;
    #pragma unroll
    for (int f = 0; f < 14; ++f) {
        #pragma unroll
        for (int r = 0; r < 4; ++r) {
            const int m = 16 * f + kq * 4 + r;
            P[((size_t)m * S_CHUNKS + s) * NCOL + col] = f32_to_bf16(acc[f][r]);
        }
    }
}

// ======================= Kernel 2: partial reduce + bias + iSWT =======================
__device__ const float REC_LO[8] = {
     0.23037781330885523f,  0.7148465705525415f,   0.6308807679295904f,
    -0.02798376941698385f, -0.18703481171888114f,  0.030841381835986965f,
     0.032883011666982945f, -0.010597401784997278f };
__device__ const float REC_HI[8] = {
     0.010597401784997278f, 0.032883011666982945f, -0.030841381835986965f,
    -0.18703481171888114f,  0.02798376941698385f,   0.6308807679295904f,
    -0.7148465705525415f,   0.23037781330885523f };

__global__ __launch_bounds__(1024) void reduce_iswt(
    const uint16_t* __restrict__ P,    // (224, 48, 1344) bf16
    const float* __restrict__ bias,    // (4, 336) flat == flat col
    float* __restrict__ out)           // (224, 336)
{
    __shared__ float coeff[NCOL];
    __shared__ float buf[2][PRED];

    const int row = blockIdx.x;
    const int tid = threadIdx.x;
    const uint32_t* pr = (const uint32_t*)(P + (size_t)row * S_CHUNKS * NCOL);

    if (tid < NCOL / 2) {
        float a0 = 0.f, a1 = 0.f;
        #pragma unroll 8
        for (int s = 0; s < S_CHUNKS; ++s) {
            const uint32_t v = pr[s * (NCOL / 2) + tid];
            a0 += bf16_to_f32((uint16_t)(v & 0xffff));
            a1 += bf16_to_f32((uint16_t)(v >> 16));
        }
        coeff[2 * tid]     = a0 + bias[2 * tid];
        coeff[2 * tid + 1] = a1 + bias[2 * tid + 1];
    }
    __syncthreads();

    if (tid < PRED) buf[0][tid] = coeff[tid];   // band 0 = cA
    __syncthreads();

    int curb = 0;
    for (int j = 3; j >= 1; --j) {
        const int step = 1 << (j - 1);              // 4, 2, 1
        const int M    = PRED / step;               // 84, 168, 336
        const float* cd  = &coeff[(4 - j) * PRED];  // cD3, cD2, cD1
        const float* cur = buf[curb];
        float* nxt       = buf[curb ^ 1];
        if (tid < PRED) {
            const int t = tid;
            const int sidx = t & (step - 1);
            const int m = t / step;
            const int mm1 = (m == 0) ? (M - 1) : (m - 1);
            float x1 = 0.f, x2 = 0.f;
            #pragma unroll
            for (int k = 0; k < 8; ++k) {
                int i1 = m + 3 - k;  if (i1 < 0) i1 += M; else if (i1 >= M) i1 -= M;
                if ((i1 & 1) == 0) {
                    const int pos = i1 * step + sidx;
                    x1 += cur[pos] * REC_LO[k] + cd[pos] * REC_HI[k];
                }
                int i2 = mm1 + 3 - k;  if (i2 < 0) i2 += M; else if (i2 >= M) i2 -= M;
                if ((i2 & 1) == 0) {
                    const int pos = (i2 + 1) * step + sidx;
                    x2 += cur[pos] * REC_LO[k] + cd[pos] * REC_HI[k];
                }
            }
            nxt[t] = 0.5f * (x1 + x2);
        }
        __syncthreads();
        curb ^= 1;
    }

    if (tid < PRED) out[(size_t)row * PRED + tid] = buf[curb][tid];
}

// ======================= launch =======================
extern "C" void kernel_launch(void* const* d_in, const int* in_sizes, int n_in,
                              void* d_out, int out_size, void* d_ws, size_t ws_size,
                              hipStream_t stream) {
    const float* X    = (const float*)d_in[0];   // (224, 49152)
    const float* W    = (const float*)d_in[1];   // (4, 49152, 336)
    const float* bias = (const float*)d_in[2];   // (4, 336)
    float* out        = (float*)d_out;           // (224, 336)
    uint16_t* P       = (uint16_t*)d_ws;                          // 29 MB partials
    uint16_t* Xb      = (uint16_t*)((char*)d_ws + XB_OFFSET);     // 22 MB bf16 X

    cvt_x       <<<5376, 256, 0, stream>>>(X, Xb);
    gemm_partial<<<21 * S_CHUNKS, 256, 0, stream>>>(Xb, W, P);
    reduce_iswt <<<M_ROWS, 1024, 0, stream>>>(P, bias, out);
}